// Round 5
// baseline (308.217 us; speedup 1.0000x reference)
//
#include <hip/hip_runtime.h>
#include <hip/hip_fp16.h>

#define N_NODES 50000
#define N_EDGES 600000
#define N_GRAPHS 64
#define HID 128
#define OUT_C 32

#define N_SCAN_BLOCKS ((N_NODES + 255) / 256)   // 196
#define SCAN_FLAG 0x40000000

typedef __attribute__((ext_vector_type(8))) _Float16 half8;
typedef __attribute__((ext_vector_type(4))) float f32x4;

// zero region layout (contiguous ints): degi[50000] cursor[50000] bsum[196] pooled[8192]
#define ZERO_INTS (2 * N_NODES + N_SCAN_BLOCKS + N_GRAPHS * HID)

// ================= zero counters + pooled accum =================
__global__ __launch_bounds__(256) void zero_kernel(int* __restrict__ zb) {
    int i = blockIdx.x * 256 + threadIdx.x;
    if (i < ZERO_INTS) zb[i] = 0;
}

// ================= degrees + graph boundaries + weight casts (ride along) =================
#define DEG_BLOCKS ((N_EDGES + 255) / 256)       // 2344
#define GST_BLOCKS ((N_NODES + 256) / 256)       // 196

__global__ __launch_bounds__(256) void deg_gst_w(
    const int* __restrict__ dst, int* __restrict__ degi,
    const int* __restrict__ batch, int* __restrict__ gstart,
    const float* __restrict__ W1l, const float* __restrict__ W1r,
    const float* __restrict__ W2l, const float* __restrict__ W2r,
    __half* __restrict__ Wt1, __half* __restrict__ Wt2) {
    const int b = blockIdx.x;
    const int t = threadIdx.x;
    if (b < DEG_BLOCKS) {
        int e = b * 256 + t;
        if (e < N_EDGES) atomicAdd(&degi[dst[e]], 1);
    } else if (b < DEG_BLOCKS + GST_BLOCKS) {
        int i = (b - DEG_BLOCKS) * 256 + t;
        if (i <= N_NODES) {
            if (i == 0) {
                int b1 = batch[0];
                for (int g = 0; g <= b1; ++g) gstart[g] = 0;
            } else if (i == N_NODES) {
                int b0 = batch[N_NODES - 1];
                for (int g = b0 + 1; g <= N_GRAPHS; ++g) gstart[g] = N_NODES;
            } else {
                int b0 = batch[i - 1], b1 = batch[i];
                for (int g = b0 + 1; g <= b1; ++g) gstart[g] = i;
            }
        }
    } else {
        int local = (b - DEG_BLOCKS - GST_BLOCKS) * 256 + t;
        for (int i = local; i < 65536; i += 4096) {
            int which = i >> 15;
            int j = i & 32767;
            int n = j >> 8, k = j & 255;
            const float* Wl = which ? W2l : W1l;
            const float* Wr = which ? W2r : W1r;
            float a = (k < 128) ? Wl[n * 128 + k] : Wr[n * 128 + (k - 128)];
            (which ? Wt2 : Wt1)[j] = __float2half(a);
        }
    }
}

// ================= CSR: single-dispatch scan (decoupled lookback) =================
__global__ __launch_bounds__(256) void scan_fused(
    const int* __restrict__ deg, int* __restrict__ bsum,
    int* __restrict__ rowptr, float* __restrict__ invdeg) {
    __shared__ int s[256];
    const int b = blockIdx.x;
    const int t = threadIdx.x;
    const int idx = b * 256 + t;
    const int v = (idx < N_NODES) ? deg[idx] : 0;
    s[t] = v;
    __syncthreads();
    for (int off = 1; off < 256; off <<= 1) {
        int u = (t >= off) ? s[t - off] : 0;
        __syncthreads();
        s[t] += u;
        __syncthreads();
    }
    const int incl = s[t];
    if (t == 255) atomicExch(&bsum[b], incl | SCAN_FLAG);

    int pv = 0;
    if (t < 64) {
        for (int f = t; f < b; f += 64) {
            int w;
            while (!((w = atomicAdd(&bsum[f], 0)) & SCAN_FLAG)) {
                __builtin_amdgcn_s_sleep(2);
            }
            pv += w & ~SCAN_FLAG;
        }
        for (int off = 32; off > 0; off >>= 1) pv += __shfl_down(pv, off);
        if (t == 0) s[0] = pv;
    }
    __syncthreads();
    const int boffs = s[0];

    if (idx < N_NODES) {
        rowptr[idx] = boffs + incl - v;
        invdeg[idx] = 1.0f / fmaxf((float)v, 1.0f);
    }
    if (b == N_SCAN_BLOCKS - 1 && t == 255) rowptr[N_NODES] = boffs + incl;
}

// ================= CSR fill + x->fp16 cast (ride along) =================
__global__ __launch_bounds__(256) void fill_cast(
    const int* __restrict__ src, const int* __restrict__ dst,
    const int* __restrict__ rowptr, int* __restrict__ cursor,
    int* __restrict__ eidx,
    const float* __restrict__ x, __half* __restrict__ xh) {
    const int b = blockIdx.x;
    const int t = threadIdx.x;
    if (b < DEG_BLOCKS) {
        int e = b * 256 + t;
        if (e < N_EDGES) {
            int d = dst[e];
            int pos = atomicAdd(&cursor[d], 1);
            eidx[rowptr[d] + pos] = src[e];
        }
    } else {
        int i = ((b - DEG_BLOCKS) * 256 + t) * 4;
        if (i < N_NODES * 128) {
            float4 v = *(const float4*)(x + i);
            __half2 a = __floats2half2_rn(v.x, v.y);
            __half2 c = __floats2half2_rn(v.z, v.w);
            uint2 st;
            st.x = *(const unsigned int*)&a;
            st.y = *(const unsigned int*)&c;
            *(uint2*)(xh + i) = st;
        }
    }
}

// ================= fused: R2 gather (16-lane/node, 1-round) -> MFMA -> epilogue ======
// LDS: Ms only (16KB). B weights (64KB, L2-hot, shared by all 782 blocks) from global.
// __launch_bounds__(256,4): VGPR cap 128 (R2 measured 88 -> no spill), 4 blocks/CU.
// Ms swizzle (both sides): byte_off ^= (row&7)<<4 within each 256B row.
#define GBM 64

__global__ __launch_bounds__(256, 4) void sage_fused(
    const __half* __restrict__ feat16, const int* __restrict__ rowptr,
    const int* __restrict__ eidx, const float* __restrict__ invdeg,
    const __half* __restrict__ Wt, const float* __restrict__ bias,
    __half* __restrict__ out16,
    const int* __restrict__ batch, float* __restrict__ pooled,
    int M, int do_pool) {
    __shared__ __align__(16) __half Ms[64 * 128];    // mean tile / pool staging

    const int tid = threadIdx.x;
    const int wave = tid >> 6;
    const int lane = tid & 63;
    const int l15 = lane & 15;
    const int quad = lane >> 4;
    const int row0 = blockIdx.x * GBM;

    // ---- aggregate: 16 groups x 4 nodes each into Ms ----
    const int g16 = tid >> 4;          // 0..15
    const int sub = tid & 15;
    const int gbase = lane & 48;
    const size_t coff = (size_t)sub * 8;   // halves

    int begq[4], endq[4], pre0q[4], pre1q[4];
#pragma unroll
    for (int q = 0; q < 4; ++q) {
        int node = row0 + g16 + 16 * q;
        int bq = 0, eq = 0;
        if (node < M) { bq = rowptr[node]; eq = rowptr[node + 1]; }
        begq[q] = bq; endq[q] = eq;
    }
#pragma unroll
    for (int q = 0; q < 4; ++q) {
        int bq = begq[q], eq = endq[q];
        pre0q[q] = (eq > bq) ? eidx[min(bq + sub,      eq - 1)] : 0;
        pre1q[q] = (eq > bq) ? eidx[min(bq + 16 + sub, eq - 1)] : 0;
    }

#pragma unroll
    for (int q = 0; q < 4; ++q) {
        const int nloc = g16 + 16 * q;
        const int node = row0 + nloc;
        const int beg = begq[q], end = endq[q];
        const int deg = end - beg;

        float4 a[4], bb[4];
#pragma unroll
        for (int g = 0; g < 4; ++g) { a[g] = (float4){0.f,0.f,0.f,0.f}; bb[g] = (float4){0.f,0.f,0.f,0.f}; }

        for (int j0 = 0; j0 < deg; j0 += 16) {
            int idx[16];
            if (j0 == 0) {
#pragma unroll
                for (int k = 0; k < 16; ++k) idx[k] = __shfl(pre0q[q], gbase + k);
            } else if (j0 == 16) {
#pragma unroll
                for (int k = 0; k < 16; ++k) idx[k] = __shfl(pre1q[q], gbase + k);
            } else {
#pragma unroll
                for (int k = 0; k < 16; ++k) idx[k] = eidx[min(beg + j0 + k, end - 1)];
            }
            half8 v[16];
#pragma unroll
            for (int k = 0; k < 16; ++k)
                v[k] = *(const half8*)(feat16 + (size_t)idx[k] * 128 + coff);
            const int rem = deg - j0;
#pragma unroll
            for (int k = 0; k < 16; ++k) {
                const float w = (k < rem) ? 1.0f : 0.0f;
                const int g = k & 3;
                a[g].x  += w * (float)v[k][0];
                a[g].y  += w * (float)v[k][1];
                a[g].z  += w * (float)v[k][2];
                a[g].w  += w * (float)v[k][3];
                bb[g].x += w * (float)v[k][4];
                bb[g].y += w * (float)v[k][5];
                bb[g].z += w * (float)v[k][6];
                bb[g].w += w * (float)v[k][7];
            }
        }

        const float sc = (node < M) ? invdeg[node] : 1.0f;
        half8 r;
        r[0] = (_Float16)(((a[0].x + a[1].x) + (a[2].x + a[3].x)) * sc);
        r[1] = (_Float16)(((a[0].y + a[1].y) + (a[2].y + a[3].y)) * sc);
        r[2] = (_Float16)(((a[0].z + a[1].z) + (a[2].z + a[3].z)) * sc);
        r[3] = (_Float16)(((a[0].w + a[1].w) + (a[2].w + a[3].w)) * sc);
        r[4] = (_Float16)(((bb[0].x + bb[1].x) + (bb[2].x + bb[3].x)) * sc);
        r[5] = (_Float16)(((bb[0].y + bb[1].y) + (bb[2].y + bb[3].y)) * sc);
        r[6] = (_Float16)(((bb[0].z + bb[1].z) + (bb[2].z + bb[3].z)) * sc);
        r[7] = (_Float16)(((bb[0].w + bb[1].w) + (bb[2].w + bb[3].w)) * sc);
        int moff = (nloc * 256 + (int)sub * 16) ^ ((nloc & 7) << 4);
        *(half8*)((char*)Ms + moff) = r;
    }

    __syncthreads();

    // ---- GEMM: A = [Ms | feat16], B = Wt from global (L2-hot broadcast) ----
    const int arow = wave * 16 + l15;
    const int gi_a = min(row0 + arow, M - 1);
    half8 af[8];
#pragma unroll
    for (int kb = 0; kb < 4; ++kb) {
        int off = (arow * 256 + kb * 64 + quad * 16) ^ ((arow & 7) << 4);
        af[kb] = *(const half8*)((const char*)Ms + off);
    }
#pragma unroll
    for (int kb = 4; kb < 8; ++kb) {
        af[kb] = *(const half8*)(feat16 + (size_t)gi_a * 128 + (kb - 4) * 32 + quad * 8);
    }

    f32x4 acc[8];
#pragma unroll
    for (int t = 0; t < 8; ++t) acc[t] = (f32x4){0.f, 0.f, 0.f, 0.f};

#pragma unroll
    for (int t = 0; t < 8; ++t) {
        const int n = t * 16 + l15;
        half8 bf0 = *(const half8*)(Wt + (size_t)n * 256 + 0 * 32 + quad * 8);
        half8 bf1 = *(const half8*)(Wt + (size_t)n * 256 + 1 * 32 + quad * 8);
        half8 bf2 = *(const half8*)(Wt + (size_t)n * 256 + 2 * 32 + quad * 8);
        half8 bf3 = *(const half8*)(Wt + (size_t)n * 256 + 3 * 32 + quad * 8);
        half8 bf4 = *(const half8*)(Wt + (size_t)n * 256 + 4 * 32 + quad * 8);
        half8 bf5 = *(const half8*)(Wt + (size_t)n * 256 + 5 * 32 + quad * 8);
        half8 bf6 = *(const half8*)(Wt + (size_t)n * 256 + 6 * 32 + quad * 8);
        half8 bf7 = *(const half8*)(Wt + (size_t)n * 256 + 7 * 32 + quad * 8);
        acc[t] = __builtin_amdgcn_mfma_f32_16x16x32_f16(af[0], bf0, acc[t], 0, 0, 0);
        acc[t] = __builtin_amdgcn_mfma_f32_16x16x32_f16(af[1], bf1, acc[t], 0, 0, 0);
        acc[t] = __builtin_amdgcn_mfma_f32_16x16x32_f16(af[2], bf2, acc[t], 0, 0, 0);
        acc[t] = __builtin_amdgcn_mfma_f32_16x16x32_f16(af[3], bf3, acc[t], 0, 0, 0);
        acc[t] = __builtin_amdgcn_mfma_f32_16x16x32_f16(af[4], bf4, acc[t], 0, 0, 0);
        acc[t] = __builtin_amdgcn_mfma_f32_16x16x32_f16(af[5], bf5, acc[t], 0, 0, 0);
        acc[t] = __builtin_amdgcn_mfma_f32_16x16x32_f16(af[6], bf6, acc[t], 0, 0, 0);
        acc[t] = __builtin_amdgcn_mfma_f32_16x16x32_f16(af[7], bf7, acc[t], 0, 0, 0);
    }

    if (!do_pool) {
        // ---- epilogue: bias + relu -> out16 ----
#pragma unroll
        for (int r = 0; r < 4; ++r) {
            int gi = row0 + wave * 16 + quad * 4 + r;
            if (gi < M) {
#pragma unroll
                for (int t = 0; t < 8; ++t) {
                    int col = t * 16 + l15;
                    float v = fmaxf(acc[t][r] + bias[col], 0.f);
                    out16[(size_t)gi * 128 + col] = __float2half(v);
                }
            }
        }
    } else {
        // ---- epilogue: bias + relu -> Ms (fp16, swizzled), then pool over graph segments ----
        __syncthreads();   // all Ms(A) reads complete
#pragma unroll
        for (int r = 0; r < 4; ++r) {
            int lrow = wave * 16 + quad * 4 + r;
            int gi = row0 + lrow;
#pragma unroll
            for (int t = 0; t < 8; ++t) {
                int col = t * 16 + l15;
                float v = fmaxf(acc[t][r] + bias[col], 0.f);
                if (gi >= M) v = 0.f;
                int off = (lrow * 256 + col * 2) ^ ((lrow & 7) << 4);
                *(__half*)((char*)Ms + off) = __float2half(v);
            }
        }
        __syncthreads();
        if (tid < 128) {
            const int col = tid;
            int cur = batch[min(row0, M - 1)];
            float s = 0.f;
            for (int r = 0; r < 64; ++r) {
                int gr = batch[min(row0 + r, M - 1)];
                if (gr != cur) {
                    atomicAdd(&pooled[cur * 128 + col], s);
                    s = 0.f; cur = gr;
                }
                int off = (r * 256 + col * 2) ^ ((r & 7) << 4);
                s += __half2float(*(const __half*)((const char*)Ms + off));
            }
            atomicAdd(&pooled[cur * 128 + col], s);
        }
    }
}

// ================= final linear =================
__global__ void final_kernel(const float* __restrict__ pooled,
                             const int* __restrict__ gstart,
                             const float* __restrict__ Wlin, const float* __restrict__ blin,
                             float* __restrict__ out) {
    int g = blockIdx.x;
    int j = threadIdx.x;               // 0..31
    float inv = 1.0f / fmaxf((float)(gstart[g + 1] - gstart[g]), 1.0f);
    float sum = blin[j];
    const float* w = Wlin + j * 128;
    const float* p = pooled + (size_t)g * 128;
    for (int c = 0; c < 128; ++c) {
        sum += p[c] * inv * w[c];
    }
    out[g * 32 + j] = sum;
}

extern "C" void kernel_launch(void* const* d_in, const int* in_sizes, int n_in,
                              void* d_out, int out_size, void* d_ws, size_t ws_size,
                              hipStream_t stream) {
    const float* x    = (const float*)d_in[0];
    const int*   src  = (const int*)d_in[1];
    const int*   dst  = ((const int*)d_in[1]) + N_EDGES;
    const int*   batch= (const int*)d_in[2];
    const float* W1l  = (const float*)d_in[3];
    const float* b1   = (const float*)d_in[4];
    const float* W1r  = (const float*)d_in[5];
    const float* W2l  = (const float*)d_in[6];
    const float* b2   = (const float*)d_in[7];
    const float* W2r  = (const float*)d_in[8];
    const float* Wlin = (const float*)d_in[9];
    const float* blin = (const float*)d_in[10];
    float* out = (float*)d_out;

    __half* xh     = (__half*)d_ws;                 // 6,400,000 h
    __half* h1_16  = xh + 6400000;                  // 6,400,000 h
    __half* Wt1    = h1_16 + 6400000;               // 32,768 h
    __half* Wt2    = Wt1 + 32768;                   // 32,768 h
    float* invdeg  = (float*)(Wt2 + 32768);         // 50,000 f
    int*   gstart  = (int*)(invdeg + N_NODES);      // 65 i
    // contiguous zero region: degi, cursor, bsum, pooled
    int*   degi    = gstart + 65;                   // 50,000 i
    int*   cursor  = degi + N_NODES;                // 50,000 i
    int*   bsum    = cursor + N_NODES;              // 196 i
    float* pooled  = (float*)(bsum + N_SCAN_BLOCKS);// 8,192 f (zeroed)
    int*   rowptr  = (int*)(pooled + N_GRAPHS*HID); // 50,001 i
    int*   eidx    = rowptr + N_NODES + 1;          // 600,000 i

    // 1) zero counters + pooled accumulators
    zero_kernel<<<(ZERO_INTS + 255) / 256, 256, 0, stream>>>(degi);

    // 2) degrees + graph boundaries + weight casts
    deg_gst_w<<<DEG_BLOCKS + GST_BLOCKS + 16, 256, 0, stream>>>(
        dst, degi, batch, gstart, W1l, W1r, W2l, W2r, Wt1, Wt2);

    // 3) fused lookback scan
    scan_fused<<<N_SCAN_BLOCKS, 256, 0, stream>>>(degi, bsum, rowptr, invdeg);

    // 4) CSR fill + x->fp16 cast
    fill_cast<<<DEG_BLOCKS + (N_NODES * 128 / 4 + 255) / 256, 256, 0, stream>>>(
        src, dst, rowptr, cursor, eidx, x, xh);

    const int grid = (N_NODES + GBM - 1) / GBM;   // 782

    // 5) layer 1: agg + gemm fused
    sage_fused<<<grid, 256, 0, stream>>>(
        xh, rowptr, eidx, invdeg, Wt1, b1, h1_16, batch, pooled, N_NODES, 0);

    // 6) layer 2: agg + gemm + pool fused
    sage_fused<<<grid, 256, 0, stream>>>(
        h1_16, rowptr, eidx, invdeg, Wt2, b2, (__half*)0, batch, pooled, N_NODES, 1);

    // 7) final linear
    final_kernel<<<N_GRAPHS, 32, 0, stream>>>(pooled, gstart, Wlin, blin, out);
}

// Round 6
// 277.759 us; speedup vs baseline: 1.1097x; 1.1097x over previous
//
#include <hip/hip_runtime.h>
#include <hip/hip_fp16.h>

#define N_NODES 50000
#define N_EDGES 600000
#define N_GRAPHS 64
#define HID 128
#define OUT_C 32

#define N_SCAN_BLOCKS ((N_NODES + 255) / 256)   // 196
#define SCAN_FLAG 0x40000000

typedef __attribute__((ext_vector_type(8))) _Float16 half8;
typedef __attribute__((ext_vector_type(4))) float f32x4;

// zero region layout (contiguous ints): degi[50000] cursor[50000] bsum[196] pooled[8192]
#define ZERO_INTS (2 * N_NODES + N_SCAN_BLOCKS + N_GRAPHS * HID)

// ================= zero counters + pooled accum =================
__global__ __launch_bounds__(256) void zero_kernel(int* __restrict__ zb) {
    int i = blockIdx.x * 256 + threadIdx.x;
    if (i < ZERO_INTS) zb[i] = 0;
}

// ================= degrees + graph boundaries + weight casts (ride along) =================
#define DEG_BLOCKS ((N_EDGES + 255) / 256)       // 2344
#define GST_BLOCKS ((N_NODES + 256) / 256)       // 196

__global__ __launch_bounds__(256) void deg_gst_w(
    const int* __restrict__ dst, int* __restrict__ degi,
    const int* __restrict__ batch, int* __restrict__ gstart,
    const float* __restrict__ W1l, const float* __restrict__ W1r,
    const float* __restrict__ W2l, const float* __restrict__ W2r,
    __half* __restrict__ Wt1, __half* __restrict__ Wt2) {
    const int b = blockIdx.x;
    const int t = threadIdx.x;
    if (b < DEG_BLOCKS) {
        int e = b * 256 + t;
        if (e < N_EDGES) atomicAdd(&degi[dst[e]], 1);
    } else if (b < DEG_BLOCKS + GST_BLOCKS) {
        int i = (b - DEG_BLOCKS) * 256 + t;
        if (i <= N_NODES) {
            if (i == 0) {
                int b1 = batch[0];
                for (int g = 0; g <= b1; ++g) gstart[g] = 0;
            } else if (i == N_NODES) {
                int b0 = batch[N_NODES - 1];
                for (int g = b0 + 1; g <= N_GRAPHS; ++g) gstart[g] = N_NODES;
            } else {
                int b0 = batch[i - 1], b1 = batch[i];
                for (int g = b0 + 1; g <= b1; ++g) gstart[g] = i;
            }
        }
    } else {
        int local = (b - DEG_BLOCKS - GST_BLOCKS) * 256 + t;
        for (int i = local; i < 65536; i += 4096) {
            int which = i >> 15;
            int j = i & 32767;
            int n = j >> 8, k = j & 255;
            const float* Wl = which ? W2l : W1l;
            const float* Wr = which ? W2r : W1r;
            float a = (k < 128) ? Wl[n * 128 + k] : Wr[n * 128 + (k - 128)];
            (which ? Wt2 : Wt1)[j] = __float2half(a);
        }
    }
}

// ================= CSR: single-dispatch scan (decoupled lookback) =================
__global__ __launch_bounds__(256) void scan_fused(
    const int* __restrict__ deg, int* __restrict__ bsum,
    int* __restrict__ rowptr, float* __restrict__ invdeg) {
    __shared__ int s[256];
    const int b = blockIdx.x;
    const int t = threadIdx.x;
    const int idx = b * 256 + t;
    const int v = (idx < N_NODES) ? deg[idx] : 0;
    s[t] = v;
    __syncthreads();
    for (int off = 1; off < 256; off <<= 1) {
        int u = (t >= off) ? s[t - off] : 0;
        __syncthreads();
        s[t] += u;
        __syncthreads();
    }
    const int incl = s[t];
    if (t == 255) atomicExch(&bsum[b], incl | SCAN_FLAG);

    int pv = 0;
    if (t < 64) {
        for (int f = t; f < b; f += 64) {
            int w;
            while (!((w = atomicAdd(&bsum[f], 0)) & SCAN_FLAG)) {
                __builtin_amdgcn_s_sleep(2);
            }
            pv += w & ~SCAN_FLAG;
        }
        for (int off = 32; off > 0; off >>= 1) pv += __shfl_down(pv, off);
        if (t == 0) s[0] = pv;
    }
    __syncthreads();
    const int boffs = s[0];

    if (idx < N_NODES) {
        rowptr[idx] = boffs + incl - v;
        invdeg[idx] = 1.0f / fmaxf((float)v, 1.0f);
    }
    if (b == N_SCAN_BLOCKS - 1 && t == 255) rowptr[N_NODES] = boffs + incl;
}

// ================= CSR fill + x->fp16 cast (ride along) =================
__global__ __launch_bounds__(256) void fill_cast(
    const int* __restrict__ src, const int* __restrict__ dst,
    const int* __restrict__ rowptr, int* __restrict__ cursor,
    int* __restrict__ eidx,
    const float* __restrict__ x, __half* __restrict__ xh) {
    const int b = blockIdx.x;
    const int t = threadIdx.x;
    if (b < DEG_BLOCKS) {
        int e = b * 256 + t;
        if (e < N_EDGES) {
            int d = dst[e];
            int pos = atomicAdd(&cursor[d], 1);
            eidx[rowptr[d] + pos] = src[e];
        }
    } else {
        int i = ((b - DEG_BLOCKS) * 256 + t) * 4;
        if (i < N_NODES * 128) {
            float4 v = *(const float4*)(x + i);
            __half2 a = __floats2half2_rn(v.x, v.y);
            __half2 c = __floats2half2_rn(v.z, v.w);
            uint2 st;
            st.x = *(const unsigned int*)&a;
            st.y = *(const unsigned int*)&c;
            *(uint2*)(xh + i) = st;
        }
    }
}

// ================= fused: R2 gather (16-lane/node, 1-round) -> MFMA -> epilogue ======
// LDS: Ms only (16KB). B weights (64KB, L2-hot, shared by all 782 blocks) from global.
// __launch_bounds__(256,3): VGPR cap ~168 (demand ~130 -> NO spill; (256,4)'s cap 128
// spilled 37MB twice, R3+R5). 3 blocks/CU = 12 waves/CU, 1.5x R2 residency.
// Ms swizzle (both sides): byte_off ^= (row&7)<<4 within each 256B row.
#define GBM 64

__global__ __launch_bounds__(256, 3) void sage_fused(
    const __half* __restrict__ feat16, const int* __restrict__ rowptr,
    const int* __restrict__ eidx, const float* __restrict__ invdeg,
    const __half* __restrict__ Wt, const float* __restrict__ bias,
    __half* __restrict__ out16,
    const int* __restrict__ batch, float* __restrict__ pooled,
    int M, int do_pool) {
    __shared__ __align__(16) __half Ms[64 * 128];    // mean tile / pool staging

    const int tid = threadIdx.x;
    const int wave = tid >> 6;
    const int lane = tid & 63;
    const int l15 = lane & 15;
    const int quad = lane >> 4;
    const int row0 = blockIdx.x * GBM;

    // ---- aggregate: 16 groups x 4 nodes each into Ms ----
    const int g16 = tid >> 4;          // 0..15
    const int sub = tid & 15;
    const int gbase = lane & 48;
    const size_t coff = (size_t)sub * 8;   // halves

    int begq[4], endq[4], pre0q[4], pre1q[4];
#pragma unroll
    for (int q = 0; q < 4; ++q) {
        int node = row0 + g16 + 16 * q;
        int bq = 0, eq = 0;
        if (node < M) { bq = rowptr[node]; eq = rowptr[node + 1]; }
        begq[q] = bq; endq[q] = eq;
    }
#pragma unroll
    for (int q = 0; q < 4; ++q) {
        int bq = begq[q], eq = endq[q];
        pre0q[q] = (eq > bq) ? eidx[min(bq + sub,      eq - 1)] : 0;
        pre1q[q] = (eq > bq) ? eidx[min(bq + 16 + sub, eq - 1)] : 0;
    }

#pragma unroll
    for (int q = 0; q < 4; ++q) {
        const int nloc = g16 + 16 * q;
        const int node = row0 + nloc;
        const int beg = begq[q], end = endq[q];
        const int deg = end - beg;

        float4 a[4], bb[4];
#pragma unroll
        for (int g = 0; g < 4; ++g) { a[g] = (float4){0.f,0.f,0.f,0.f}; bb[g] = (float4){0.f,0.f,0.f,0.f}; }

        for (int j0 = 0; j0 < deg; j0 += 16) {
            int idx[16];
            if (j0 == 0) {
#pragma unroll
                for (int k = 0; k < 16; ++k) idx[k] = __shfl(pre0q[q], gbase + k);
            } else if (j0 == 16) {
#pragma unroll
                for (int k = 0; k < 16; ++k) idx[k] = __shfl(pre1q[q], gbase + k);
            } else {
#pragma unroll
                for (int k = 0; k < 16; ++k) idx[k] = eidx[min(beg + j0 + k, end - 1)];
            }
            half8 v[16];
#pragma unroll
            for (int k = 0; k < 16; ++k)
                v[k] = *(const half8*)(feat16 + (size_t)idx[k] * 128 + coff);
            const int rem = deg - j0;
#pragma unroll
            for (int k = 0; k < 16; ++k) {
                const float w = (k < rem) ? 1.0f : 0.0f;
                const int g = k & 3;
                a[g].x  += w * (float)v[k][0];
                a[g].y  += w * (float)v[k][1];
                a[g].z  += w * (float)v[k][2];
                a[g].w  += w * (float)v[k][3];
                bb[g].x += w * (float)v[k][4];
                bb[g].y += w * (float)v[k][5];
                bb[g].z += w * (float)v[k][6];
                bb[g].w += w * (float)v[k][7];
            }
        }

        const float sc = (node < M) ? invdeg[node] : 1.0f;
        half8 r;
        r[0] = (_Float16)(((a[0].x + a[1].x) + (a[2].x + a[3].x)) * sc);
        r[1] = (_Float16)(((a[0].y + a[1].y) + (a[2].y + a[3].y)) * sc);
        r[2] = (_Float16)(((a[0].z + a[1].z) + (a[2].z + a[3].z)) * sc);
        r[3] = (_Float16)(((a[0].w + a[1].w) + (a[2].w + a[3].w)) * sc);
        r[4] = (_Float16)(((bb[0].x + bb[1].x) + (bb[2].x + bb[3].x)) * sc);
        r[5] = (_Float16)(((bb[0].y + bb[1].y) + (bb[2].y + bb[3].y)) * sc);
        r[6] = (_Float16)(((bb[0].z + bb[1].z) + (bb[2].z + bb[3].z)) * sc);
        r[7] = (_Float16)(((bb[0].w + bb[1].w) + (bb[2].w + bb[3].w)) * sc);
        int moff = (nloc * 256 + (int)sub * 16) ^ ((nloc & 7) << 4);
        *(half8*)((char*)Ms + moff) = r;
    }

    __syncthreads();

    // ---- GEMM: A = [Ms | feat16], B = Wt from global (L2-hot broadcast) ----
    const int arow = wave * 16 + l15;
    const int gi_a = min(row0 + arow, M - 1);
    half8 af[8];
#pragma unroll
    for (int kb = 0; kb < 4; ++kb) {
        int off = (arow * 256 + kb * 64 + quad * 16) ^ ((arow & 7) << 4);
        af[kb] = *(const half8*)((const char*)Ms + off);
    }
#pragma unroll
    for (int kb = 4; kb < 8; ++kb) {
        af[kb] = *(const half8*)(feat16 + (size_t)gi_a * 128 + (kb - 4) * 32 + quad * 8);
    }

    f32x4 acc[8];
#pragma unroll
    for (int t = 0; t < 8; ++t) acc[t] = (f32x4){0.f, 0.f, 0.f, 0.f};

#pragma unroll
    for (int t = 0; t < 8; ++t) {
        const int n = t * 16 + l15;
        half8 bf0 = *(const half8*)(Wt + (size_t)n * 256 + 0 * 32 + quad * 8);
        half8 bf1 = *(const half8*)(Wt + (size_t)n * 256 + 1 * 32 + quad * 8);
        half8 bf2 = *(const half8*)(Wt + (size_t)n * 256 + 2 * 32 + quad * 8);
        half8 bf3 = *(const half8*)(Wt + (size_t)n * 256 + 3 * 32 + quad * 8);
        half8 bf4 = *(const half8*)(Wt + (size_t)n * 256 + 4 * 32 + quad * 8);
        half8 bf5 = *(const half8*)(Wt + (size_t)n * 256 + 5 * 32 + quad * 8);
        half8 bf6 = *(const half8*)(Wt + (size_t)n * 256 + 6 * 32 + quad * 8);
        half8 bf7 = *(const half8*)(Wt + (size_t)n * 256 + 7 * 32 + quad * 8);
        acc[t] = __builtin_amdgcn_mfma_f32_16x16x32_f16(af[0], bf0, acc[t], 0, 0, 0);
        acc[t] = __builtin_amdgcn_mfma_f32_16x16x32_f16(af[1], bf1, acc[t], 0, 0, 0);
        acc[t] = __builtin_amdgcn_mfma_f32_16x16x32_f16(af[2], bf2, acc[t], 0, 0, 0);
        acc[t] = __builtin_amdgcn_mfma_f32_16x16x32_f16(af[3], bf3, acc[t], 0, 0, 0);
        acc[t] = __builtin_amdgcn_mfma_f32_16x16x32_f16(af[4], bf4, acc[t], 0, 0, 0);
        acc[t] = __builtin_amdgcn_mfma_f32_16x16x32_f16(af[5], bf5, acc[t], 0, 0, 0);
        acc[t] = __builtin_amdgcn_mfma_f32_16x16x32_f16(af[6], bf6, acc[t], 0, 0, 0);
        acc[t] = __builtin_amdgcn_mfma_f32_16x16x32_f16(af[7], bf7, acc[t], 0, 0, 0);
    }

    if (!do_pool) {
        // ---- epilogue: bias + relu -> out16 ----
#pragma unroll
        for (int r = 0; r < 4; ++r) {
            int gi = row0 + wave * 16 + quad * 4 + r;
            if (gi < M) {
#pragma unroll
                for (int t = 0; t < 8; ++t) {
                    int col = t * 16 + l15;
                    float v = fmaxf(acc[t][r] + bias[col], 0.f);
                    out16[(size_t)gi * 128 + col] = __float2half(v);
                }
            }
        }
    } else {
        // ---- epilogue: bias + relu -> Ms (fp16, swizzled), then pool over graph segments ----
        __syncthreads();   // all Ms(A) reads complete
#pragma unroll
        for (int r = 0; r < 4; ++r) {
            int lrow = wave * 16 + quad * 4 + r;
            int gi = row0 + lrow;
#pragma unroll
            for (int t = 0; t < 8; ++t) {
                int col = t * 16 + l15;
                float v = fmaxf(acc[t][r] + bias[col], 0.f);
                if (gi >= M) v = 0.f;
                int off = (lrow * 256 + col * 2) ^ ((lrow & 7) << 4);
                *(__half*)((char*)Ms + off) = __float2half(v);
            }
        }
        __syncthreads();
        if (tid < 128) {
            const int col = tid;
            int cur = batch[min(row0, M - 1)];
            float s = 0.f;
            for (int r = 0; r < 64; ++r) {
                int gr = batch[min(row0 + r, M - 1)];
                if (gr != cur) {
                    atomicAdd(&pooled[cur * 128 + col], s);
                    s = 0.f; cur = gr;
                }
                int off = (r * 256 + col * 2) ^ ((r & 7) << 4);
                s += __half2float(*(const __half*)((const char*)Ms + off));
            }
            atomicAdd(&pooled[cur * 128 + col], s);
        }
    }
}

// ================= final linear =================
__global__ void final_kernel(const float* __restrict__ pooled,
                             const int* __restrict__ gstart,
                             const float* __restrict__ Wlin, const float* __restrict__ blin,
                             float* __restrict__ out) {
    int g = blockIdx.x;
    int j = threadIdx.x;               // 0..31
    float inv = 1.0f / fmaxf((float)(gstart[g + 1] - gstart[g]), 1.0f);
    float sum = blin[j];
    const float* w = Wlin + j * 128;
    const float* p = pooled + (size_t)g * 128;
    for (int c = 0; c < 128; ++c) {
        sum += p[c] * inv * w[c];
    }
    out[g * 32 + j] = sum;
}

extern "C" void kernel_launch(void* const* d_in, const int* in_sizes, int n_in,
                              void* d_out, int out_size, void* d_ws, size_t ws_size,
                              hipStream_t stream) {
    const float* x    = (const float*)d_in[0];
    const int*   src  = (const int*)d_in[1];
    const int*   dst  = ((const int*)d_in[1]) + N_EDGES;
    const int*   batch= (const int*)d_in[2];
    const float* W1l  = (const float*)d_in[3];
    const float* b1   = (const float*)d_in[4];
    const float* W1r  = (const float*)d_in[5];
    const float* W2l  = (const float*)d_in[6];
    const float* b2   = (const float*)d_in[7];
    const float* W2r  = (const float*)d_in[8];
    const float* Wlin = (const float*)d_in[9];
    const float* blin = (const float*)d_in[10];
    float* out = (float*)d_out;

    __half* xh     = (__half*)d_ws;                 // 6,400,000 h
    __half* h1_16  = xh + 6400000;                  // 6,400,000 h
    __half* Wt1    = h1_16 + 6400000;               // 32,768 h
    __half* Wt2    = Wt1 + 32768;                   // 32,768 h
    float* invdeg  = (float*)(Wt2 + 32768);         // 50,000 f
    int*   gstart  = (int*)(invdeg + N_NODES);      // 65 i
    // contiguous zero region: degi, cursor, bsum, pooled
    int*   degi    = gstart + 65;                   // 50,000 i
    int*   cursor  = degi + N_NODES;                // 50,000 i
    int*   bsum    = cursor + N_NODES;              // 196 i
    float* pooled  = (float*)(bsum + N_SCAN_BLOCKS);// 8,192 f (zeroed)
    int*   rowptr  = (int*)(pooled + N_GRAPHS*HID); // 50,001 i
    int*   eidx    = rowptr + N_NODES + 1;          // 600,000 i

    // 1) zero counters + pooled accumulators
    zero_kernel<<<(ZERO_INTS + 255) / 256, 256, 0, stream>>>(degi);

    // 2) degrees + graph boundaries + weight casts
    deg_gst_w<<<DEG_BLOCKS + GST_BLOCKS + 16, 256, 0, stream>>>(
        dst, degi, batch, gstart, W1l, W1r, W2l, W2r, Wt1, Wt2);

    // 3) fused lookback scan
    scan_fused<<<N_SCAN_BLOCKS, 256, 0, stream>>>(degi, bsum, rowptr, invdeg);

    // 4) CSR fill + x->fp16 cast
    fill_cast<<<DEG_BLOCKS + (N_NODES * 128 / 4 + 255) / 256, 256, 0, stream>>>(
        src, dst, rowptr, cursor, eidx, x, xh);

    const int grid = (N_NODES + GBM - 1) / GBM;   // 782

    // 5) layer 1: agg + gemm fused
    sage_fused<<<grid, 256, 0, stream>>>(
        xh, rowptr, eidx, invdeg, Wt1, b1, h1_16, batch, pooled, N_NODES, 0);

    // 6) layer 2: agg + gemm + pool fused
    sage_fused<<<grid, 256, 0, stream>>>(
        h1_16, rowptr, eidx, invdeg, Wt2, b2, (__half*)0, batch, pooled, N_NODES, 1);

    // 7) final linear
    final_kernel<<<N_GRAPHS, 32, 0, stream>>>(pooled, gstart, Wlin, blin, out);
}

// Round 7
// 270.255 us; speedup vs baseline: 1.1405x; 1.0278x over previous
//
#include <hip/hip_runtime.h>
#include <hip/hip_fp16.h>

#define N_NODES 50000
#define N_EDGES 600000
#define N_GRAPHS 64
#define HID 128
#define OUT_C 32

#define N_SCAN_BLOCKS ((N_NODES + 255) / 256)   // 196
#define SCAN_FLAG 0x40000000
#define N_TILES (N_NODES / 16)                  // 3125 (exact)
#define SAGE_BLOCKS 512                         // 2 per CU exactly

typedef __attribute__((ext_vector_type(8))) _Float16 half8;
typedef __attribute__((ext_vector_type(4))) float f32x4;

// zero region (contiguous ints): degi[50000] cursor[50000] bsum[196] pooled[8192] ctr[2]
#define ZERO_INTS (2 * N_NODES + N_SCAN_BLOCKS + N_GRAPHS * HID + 2)

// ================= zero counters + pooled accum + tile counters =================
__global__ __launch_bounds__(256) void zero_kernel(int* __restrict__ zb) {
    int i = blockIdx.x * 256 + threadIdx.x;
    if (i < ZERO_INTS) zb[i] = 0;
}

// ================= degrees + graph boundaries + weight casts (ride along) =================
#define DEG_BLOCKS ((N_EDGES + 255) / 256)       // 2344
#define GST_BLOCKS ((N_NODES + 256) / 256)       // 196

__global__ __launch_bounds__(256) void deg_gst_w(
    const int* __restrict__ dst, int* __restrict__ degi,
    const int* __restrict__ batch, int* __restrict__ gstart,
    const float* __restrict__ W1l, const float* __restrict__ W1r,
    const float* __restrict__ W2l, const float* __restrict__ W2r,
    __half* __restrict__ Wt1, __half* __restrict__ Wt2) {
    const int b = blockIdx.x;
    const int t = threadIdx.x;
    if (b < DEG_BLOCKS) {
        int e = b * 256 + t;
        if (e < N_EDGES) atomicAdd(&degi[dst[e]], 1);
    } else if (b < DEG_BLOCKS + GST_BLOCKS) {
        int i = (b - DEG_BLOCKS) * 256 + t;
        if (i <= N_NODES) {
            if (i == 0) {
                int b1 = batch[0];
                for (int g = 0; g <= b1; ++g) gstart[g] = 0;
            } else if (i == N_NODES) {
                int b0 = batch[N_NODES - 1];
                for (int g = b0 + 1; g <= N_GRAPHS; ++g) gstart[g] = N_NODES;
            } else {
                int b0 = batch[i - 1], b1 = batch[i];
                for (int g = b0 + 1; g <= b1; ++g) gstart[g] = i;
            }
        }
    } else {
        int local = (b - DEG_BLOCKS - GST_BLOCKS) * 256 + t;
        for (int i = local; i < 65536; i += 4096) {
            int which = i >> 15;
            int j = i & 32767;
            int n = j >> 8, k = j & 255;
            const float* Wl = which ? W2l : W1l;
            const float* Wr = which ? W2r : W1r;
            float a = (k < 128) ? Wl[n * 128 + k] : Wr[n * 128 + (k - 128)];
            (which ? Wt2 : Wt1)[j] = __float2half(a);
        }
    }
}

// ================= CSR: single-dispatch scan (decoupled lookback) =================
__global__ __launch_bounds__(256) void scan_fused(
    const int* __restrict__ deg, int* __restrict__ bsum,
    int* __restrict__ rowptr, float* __restrict__ invdeg) {
    __shared__ int s[256];
    const int b = blockIdx.x;
    const int t = threadIdx.x;
    const int idx = b * 256 + t;
    const int v = (idx < N_NODES) ? deg[idx] : 0;
    s[t] = v;
    __syncthreads();
    for (int off = 1; off < 256; off <<= 1) {
        int u = (t >= off) ? s[t - off] : 0;
        __syncthreads();
        s[t] += u;
        __syncthreads();
    }
    const int incl = s[t];
    if (t == 255) atomicExch(&bsum[b], incl | SCAN_FLAG);

    int pv = 0;
    if (t < 64) {
        for (int f = t; f < b; f += 64) {
            int w;
            while (!((w = atomicAdd(&bsum[f], 0)) & SCAN_FLAG)) {
                __builtin_amdgcn_s_sleep(2);
            }
            pv += w & ~SCAN_FLAG;
        }
        for (int off = 32; off > 0; off >>= 1) pv += __shfl_down(pv, off);
        if (t == 0) s[0] = pv;
    }
    __syncthreads();
    const int boffs = s[0];

    if (idx < N_NODES) {
        rowptr[idx] = boffs + incl - v;
        invdeg[idx] = 1.0f / fmaxf((float)v, 1.0f);
    }
    if (b == N_SCAN_BLOCKS - 1 && t == 255) rowptr[N_NODES] = boffs + incl;
}

// ================= CSR fill + x->fp16 cast (ride along) =================
__global__ __launch_bounds__(256) void fill_cast(
    const int* __restrict__ src, const int* __restrict__ dst,
    const int* __restrict__ rowptr, int* __restrict__ cursor,
    int* __restrict__ eidx,
    const float* __restrict__ x, __half* __restrict__ xh) {
    const int b = blockIdx.x;
    const int t = threadIdx.x;
    if (b < DEG_BLOCKS) {
        int e = b * 256 + t;
        if (e < N_EDGES) {
            int d = dst[e];
            int pos = atomicAdd(&cursor[d], 1);
            eidx[rowptr[d] + pos] = src[e];
        }
    } else {
        int i = ((b - DEG_BLOCKS) * 256 + t) * 4;
        if (i < N_NODES * 128) {
            float4 v = *(const float4*)(x + i);
            __half2 a = __floats2half2_rn(v.x, v.y);
            __half2 c = __floats2half2_rn(v.z, v.w);
            uint2 st;
            st.x = *(const unsigned int*)&a;
            st.y = *(const unsigned int*)&c;
            *(uint2*)(xh + i) = st;
        }
    }
}

// ================= persistent fused sage: Bs staged once, dynamic 16-row tiles ======
// LDS: Bs 64KB + Ms 4KB -> 68KB, 2 blocks/CU (R2's proven config). 512 blocks pop
// 3125 tiles off a global counter: tail util 0.76 -> ~0.92, Bs staged 512x not 782x.
// Per tile: 256 threads gather 16 nodes (16 lanes/node, R2 inner loop, no q-loop);
// MFMA: 4 waves share the 16 A-rows, each wave owns 2 of 8 N-col tiles.
__global__ __launch_bounds__(256, 2) void sage_persist(
    const __half* __restrict__ feat16, const int* __restrict__ rowptr,
    const int* __restrict__ eidx, const float* __restrict__ invdeg,
    const __half* __restrict__ Wt, const float* __restrict__ bias,
    __half* __restrict__ out16,
    const int* __restrict__ batch, float* __restrict__ pooled,
    int* __restrict__ ctr, int do_pool) {
    __shared__ __align__(16) __half Bs[128 * 256];   // weights, swizzled rows (512B)
    __shared__ __align__(16) __half Ms[16 * 128];    // mean tile / pool staging
    __shared__ int sTile;

    const int tid = threadIdx.x;
    const int wave = tid >> 6;
    const int lane = tid & 63;
    const int l15 = lane & 15;
    const int quad = lane >> 4;

    // ---- stage B into LDS once (swizzled) ----
    for (int id = tid; id < 128 * 32; id += 256) {
        int n = id >> 5;
        int kc16 = (id & 31) * 16;
        int off = (n * 512 + kc16) ^ ((n & 7) << 4);
        *(half8*)((char*)Bs + off) = *(const half8*)((const char*)Wt + n * 512 + kc16);
    }

    const int g16 = tid >> 4;          // 0..15: node within tile
    const int sub = tid & 15;          // 16B-chunk owner
    const int gbase = lane & 48;
    const size_t coff = (size_t)sub * 8;   // halves

    for (;;) {
        if (tid == 0) sTile = atomicAdd(ctr, 1);
        __syncthreads();               // broadcast tile; also guards Ms reuse
        const int tile = sTile;
        if (tile >= N_TILES) break;
        const int row0 = tile * 16;

        // ---- gather: 16 nodes, 16 lanes each ----
        const int node = row0 + g16;
        const int beg = rowptr[node];
        const int end = rowptr[node + 1];
        const int deg = end - beg;
        const int pre0 = (deg > 0) ? eidx[min(beg + sub,      end - 1)] : 0;
        const int pre1 = (deg > 0) ? eidx[min(beg + 16 + sub, end - 1)] : 0;

        float4 a[4], bb[4];
#pragma unroll
        for (int g = 0; g < 4; ++g) { a[g] = (float4){0.f,0.f,0.f,0.f}; bb[g] = (float4){0.f,0.f,0.f,0.f}; }

        for (int j0 = 0; j0 < deg; j0 += 16) {
            int idx[16];
            if (j0 == 0) {
#pragma unroll
                for (int k = 0; k < 16; ++k) idx[k] = __shfl(pre0, gbase + k);
            } else if (j0 == 16) {
#pragma unroll
                for (int k = 0; k < 16; ++k) idx[k] = __shfl(pre1, gbase + k);
            } else {
#pragma unroll
                for (int k = 0; k < 16; ++k) idx[k] = eidx[min(beg + j0 + k, end - 1)];
            }
            half8 v[16];
#pragma unroll
            for (int k = 0; k < 16; ++k)
                v[k] = *(const half8*)(feat16 + (size_t)idx[k] * 128 + coff);
            const int rem = deg - j0;
#pragma unroll
            for (int k = 0; k < 16; ++k) {
                const float w = (k < rem) ? 1.0f : 0.0f;
                const int g = k & 3;
                a[g].x  += w * (float)v[k][0];
                a[g].y  += w * (float)v[k][1];
                a[g].z  += w * (float)v[k][2];
                a[g].w  += w * (float)v[k][3];
                bb[g].x += w * (float)v[k][4];
                bb[g].y += w * (float)v[k][5];
                bb[g].z += w * (float)v[k][6];
                bb[g].w += w * (float)v[k][7];
            }
        }

        const float sc = invdeg[node];
        half8 r;
        r[0] = (_Float16)(((a[0].x + a[1].x) + (a[2].x + a[3].x)) * sc);
        r[1] = (_Float16)(((a[0].y + a[1].y) + (a[2].y + a[3].y)) * sc);
        r[2] = (_Float16)(((a[0].z + a[1].z) + (a[2].z + a[3].z)) * sc);
        r[3] = (_Float16)(((a[0].w + a[1].w) + (a[2].w + a[3].w)) * sc);
        r[4] = (_Float16)(((bb[0].x + bb[1].x) + (bb[2].x + bb[3].x)) * sc);
        r[5] = (_Float16)(((bb[0].y + bb[1].y) + (bb[2].y + bb[3].y)) * sc);
        r[6] = (_Float16)(((bb[0].z + bb[1].z) + (bb[2].z + bb[3].z)) * sc);
        r[7] = (_Float16)(((bb[0].w + bb[1].w) + (bb[2].w + bb[3].w)) * sc);
        int moff = (g16 * 256 + (int)sub * 16) ^ ((g16 & 7) << 4);
        *(half8*)((char*)Ms + moff) = r;

        __syncthreads();

        // ---- MFMA: A rows 0..15 shared by all waves; wave owns N-col tiles {2w,2w+1} ----
        half8 af[8];
#pragma unroll
        for (int kb = 0; kb < 4; ++kb) {
            int off = (l15 * 256 + kb * 64 + quad * 16) ^ ((l15 & 7) << 4);
            af[kb] = *(const half8*)((const char*)Ms + off);
        }
#pragma unroll
        for (int kb = 4; kb < 8; ++kb) {
            af[kb] = *(const half8*)(feat16 + (size_t)(row0 + l15) * 128 + (kb - 4) * 32 + quad * 8);
        }

        f32x4 acc[2];
        acc[0] = (f32x4){0.f, 0.f, 0.f, 0.f};
        acc[1] = (f32x4){0.f, 0.f, 0.f, 0.f};
#pragma unroll
        for (int tt = 0; tt < 2; ++tt) {
            const int n = (wave * 2 + tt) * 16 + l15;
#pragma unroll
            for (int kb = 0; kb < 8; ++kb) {
                const int boff = (n * 512 + kb * 64 + quad * 16) ^ ((n & 7) << 4);
                const half8 b = *(const half8*)((const char*)Bs + boff);
                acc[tt] = __builtin_amdgcn_mfma_f32_16x16x32_f16(af[kb], b, acc[tt], 0, 0, 0);
            }
        }

        if (!do_pool) {
#pragma unroll
            for (int tt = 0; tt < 2; ++tt) {
                const int col = (wave * 2 + tt) * 16 + l15;
#pragma unroll
                for (int rr = 0; rr < 4; ++rr) {
                    const int gi = row0 + quad * 4 + rr;
                    float v = fmaxf(acc[tt][rr] + bias[col], 0.f);
                    out16[(size_t)gi * 128 + col] = __float2half(v);
                }
            }
        } else {
            // relu -> Ms (swizzled), then pool 16 rows over graph segments
#pragma unroll
            for (int tt = 0; tt < 2; ++tt) {
                const int col = (wave * 2 + tt) * 16 + l15;
#pragma unroll
                for (int rr = 0; rr < 4; ++rr) {
                    const int lrow = quad * 4 + rr;
                    float v = fmaxf(acc[tt][rr] + bias[col], 0.f);
                    int off = (lrow * 256 + col * 2) ^ ((lrow & 7) << 4);
                    *(__half*)((char*)Ms + off) = __float2half(v);
                }
            }
            __syncthreads();
            if (tid < 128) {
                const int col = tid;
                int cur = batch[row0];
                float s = 0.f;
#pragma unroll
                for (int rr = 0; rr < 16; ++rr) {
                    int gr = batch[row0 + rr];
                    if (gr != cur) {
                        atomicAdd(&pooled[cur * 128 + col], s);
                        s = 0.f; cur = gr;
                    }
                    int off = (rr * 256 + col * 2) ^ ((rr & 7) << 4);
                    s += __half2float(*(const __half*)((const char*)Ms + off));
                }
                atomicAdd(&pooled[cur * 128 + col], s);
            }
        }
    }
}

// ================= final linear =================
__global__ void final_kernel(const float* __restrict__ pooled,
                             const int* __restrict__ gstart,
                             const float* __restrict__ Wlin, const float* __restrict__ blin,
                             float* __restrict__ out) {
    int g = blockIdx.x;
    int j = threadIdx.x;               // 0..31
    float inv = 1.0f / fmaxf((float)(gstart[g + 1] - gstart[g]), 1.0f);
    float sum = blin[j];
    const float* w = Wlin + j * 128;
    const float* p = pooled + (size_t)g * 128;
    for (int c = 0; c < 128; ++c) {
        sum += p[c] * inv * w[c];
    }
    out[g * 32 + j] = sum;
}

extern "C" void kernel_launch(void* const* d_in, const int* in_sizes, int n_in,
                              void* d_out, int out_size, void* d_ws, size_t ws_size,
                              hipStream_t stream) {
    const float* x    = (const float*)d_in[0];
    const int*   src  = (const int*)d_in[1];
    const int*   dst  = ((const int*)d_in[1]) + N_EDGES;
    const int*   batch= (const int*)d_in[2];
    const float* W1l  = (const float*)d_in[3];
    const float* b1   = (const float*)d_in[4];
    const float* W1r  = (const float*)d_in[5];
    const float* W2l  = (const float*)d_in[6];
    const float* b2   = (const float*)d_in[7];
    const float* W2r  = (const float*)d_in[8];
    const float* Wlin = (const float*)d_in[9];
    const float* blin = (const float*)d_in[10];
    float* out = (float*)d_out;

    __half* xh     = (__half*)d_ws;                 // 6,400,000 h
    __half* h1_16  = xh + 6400000;                  // 6,400,000 h
    __half* Wt1    = h1_16 + 6400000;               // 32,768 h
    __half* Wt2    = Wt1 + 32768;                   // 32,768 h
    float* invdeg  = (float*)(Wt2 + 32768);         // 50,000 f
    int*   gstart  = (int*)(invdeg + N_NODES);      // 65 i
    // contiguous zero region: degi, cursor, bsum, pooled, ctr
    int*   degi    = gstart + 65;                   // 50,000 i
    int*   cursor  = degi + N_NODES;                // 50,000 i
    int*   bsum    = cursor + N_NODES;              // 196 i
    float* pooled  = (float*)(bsum + N_SCAN_BLOCKS);// 8,192 f (zeroed)
    int*   ctr     = (int*)(pooled + N_GRAPHS*HID); // 2 i (zeroed)
    int*   rowptr  = ctr + 2;                       // 50,001 i
    int*   eidx    = rowptr + N_NODES + 1;          // 600,000 i

    // 1) zero counters + pooled accumulators + tile counters
    zero_kernel<<<(ZERO_INTS + 255) / 256, 256, 0, stream>>>(degi);

    // 2) degrees + graph boundaries + weight casts
    deg_gst_w<<<DEG_BLOCKS + GST_BLOCKS + 16, 256, 0, stream>>>(
        dst, degi, batch, gstart, W1l, W1r, W2l, W2r, Wt1, Wt2);

    // 3) fused lookback scan
    scan_fused<<<N_SCAN_BLOCKS, 256, 0, stream>>>(degi, bsum, rowptr, invdeg);

    // 4) CSR fill + x->fp16 cast
    fill_cast<<<DEG_BLOCKS + (N_NODES * 128 / 4 + 255) / 256, 256, 0, stream>>>(
        src, dst, rowptr, cursor, eidx, x, xh);

    // 5) layer 1: persistent agg + gemm fused
    sage_persist<<<SAGE_BLOCKS, 256, 0, stream>>>(
        xh, rowptr, eidx, invdeg, Wt1, b1, h1_16, batch, pooled, ctr + 0, 0);

    // 6) layer 2: persistent agg + gemm + pool fused
    sage_persist<<<SAGE_BLOCKS, 256, 0, stream>>>(
        h1_16, rowptr, eidx, invdeg, Wt2, b2, (__half*)0, batch, pooled, ctr + 1, 1);

    // 7) final linear
    final_kernel<<<N_GRAPHS, 32, 0, stream>>>(pooled, gstart, Wlin, blin, out);
}

// Round 8
// 243.500 us; speedup vs baseline: 1.2658x; 1.1099x over previous
//
#include <hip/hip_runtime.h>
#include <hip/hip_fp16.h>

#define N_NODES 50000
#define N_EDGES 600000
#define N_GRAPHS 64
#define HID 128
#define OUT_C 32

#define N_SCAN_BLOCKS ((N_NODES + 255) / 256)   // 196
#define SCAN_FLAG 0x40000000

typedef __attribute__((ext_vector_type(8))) _Float16 half8;
typedef __attribute__((ext_vector_type(4))) float f32x4;

// zero region layout (contiguous ints): degi[50000] cursor[50000] bsum[196] pooled[8192]
#define ZERO_INTS (2 * N_NODES + N_SCAN_BLOCKS + N_GRAPHS * HID)

// ================= zero counters + pooled accum =================
__global__ __launch_bounds__(256) void zero_kernel(int* __restrict__ zb) {
    int i = blockIdx.x * 256 + threadIdx.x;
    if (i < ZERO_INTS) zb[i] = 0;
}

// ================= degrees + graph boundaries + weight casts (ride along) =================
#define DEG_BLOCKS ((N_EDGES + 255) / 256)       // 2344
#define GST_BLOCKS ((N_NODES + 256) / 256)       // 196

__global__ __launch_bounds__(256) void deg_gst_w(
    const int* __restrict__ dst, int* __restrict__ degi,
    const int* __restrict__ batch, int* __restrict__ gstart,
    const float* __restrict__ W1l, const float* __restrict__ W1r,
    const float* __restrict__ W2l, const float* __restrict__ W2r,
    __half* __restrict__ Wt1, __half* __restrict__ Wt2) {
    const int b = blockIdx.x;
    const int t = threadIdx.x;
    if (b < DEG_BLOCKS) {
        int e = b * 256 + t;
        if (e < N_EDGES) atomicAdd(&degi[dst[e]], 1);
    } else if (b < DEG_BLOCKS + GST_BLOCKS) {
        int i = (b - DEG_BLOCKS) * 256 + t;
        if (i <= N_NODES) {
            if (i == 0) {
                int b1 = batch[0];
                for (int g = 0; g <= b1; ++g) gstart[g] = 0;
            } else if (i == N_NODES) {
                int b0 = batch[N_NODES - 1];
                for (int g = b0 + 1; g <= N_GRAPHS; ++g) gstart[g] = N_NODES;
            } else {
                int b0 = batch[i - 1], b1 = batch[i];
                for (int g = b0 + 1; g <= b1; ++g) gstart[g] = i;
            }
        }
    } else {
        int local = (b - DEG_BLOCKS - GST_BLOCKS) * 256 + t;
        for (int i = local; i < 65536; i += 4096) {
            int which = i >> 15;
            int j = i & 32767;
            int n = j >> 8, k = j & 255;
            const float* Wl = which ? W2l : W1l;
            const float* Wr = which ? W2r : W1r;
            float a = (k < 128) ? Wl[n * 128 + k] : Wr[n * 128 + (k - 128)];
            (which ? Wt2 : Wt1)[j] = __float2half(a);
        }
    }
}

// ================= CSR: single-dispatch scan (decoupled lookback) =================
__global__ __launch_bounds__(256) void scan_fused(
    const int* __restrict__ deg, int* __restrict__ bsum,
    int* __restrict__ rowptr, float* __restrict__ invdeg) {
    __shared__ int s[256];
    const int b = blockIdx.x;
    const int t = threadIdx.x;
    const int idx = b * 256 + t;
    const int v = (idx < N_NODES) ? deg[idx] : 0;
    s[t] = v;
    __syncthreads();
    for (int off = 1; off < 256; off <<= 1) {
        int u = (t >= off) ? s[t - off] : 0;
        __syncthreads();
        s[t] += u;
        __syncthreads();
    }
    const int incl = s[t];
    if (t == 255) atomicExch(&bsum[b], incl | SCAN_FLAG);

    int pv = 0;
    if (t < 64) {
        for (int f = t; f < b; f += 64) {
            int w;
            while (!((w = atomicAdd(&bsum[f], 0)) & SCAN_FLAG)) {
                __builtin_amdgcn_s_sleep(2);
            }
            pv += w & ~SCAN_FLAG;
        }
        for (int off = 32; off > 0; off >>= 1) pv += __shfl_down(pv, off);
        if (t == 0) s[0] = pv;
    }
    __syncthreads();
    const int boffs = s[0];

    if (idx < N_NODES) {
        rowptr[idx] = boffs + incl - v;
        invdeg[idx] = 1.0f / fmaxf((float)v, 1.0f);
    }
    if (b == N_SCAN_BLOCKS - 1 && t == 255) rowptr[N_NODES] = boffs + incl;
}

// ================= CSR fill + x->fp16 cast (ride along) =================
__global__ __launch_bounds__(256) void fill_cast(
    const int* __restrict__ src, const int* __restrict__ dst,
    const int* __restrict__ rowptr, int* __restrict__ cursor,
    int* __restrict__ eidx,
    const float* __restrict__ x, __half* __restrict__ xh) {
    const int b = blockIdx.x;
    const int t = threadIdx.x;
    if (b < DEG_BLOCKS) {
        int e = b * 256 + t;
        if (e < N_EDGES) {
            int d = dst[e];
            int pos = atomicAdd(&cursor[d], 1);
            eidx[rowptr[d] + pos] = src[e];
        }
    } else {
        int i = ((b - DEG_BLOCKS) * 256 + t) * 4;
        if (i < N_NODES * 128) {
            float4 v = *(const float4*)(x + i);
            __half2 a = __floats2half2_rn(v.x, v.y);
            __half2 c = __floats2half2_rn(v.z, v.w);
            uint2 st;
            st.x = *(const unsigned int*)&a;
            st.y = *(const unsigned int*)&c;
            *(uint2*)(xh + i) = st;
        }
    }
}

// ================= fused sage: R2 structure, B staged in TWO 32KB phases ======
// out = mean @ Wl^T + x @ Wr^T + b; K splits at 128. Bs holds only one half at a
// time: LDS = Bs 32KB + Ms 16KB = 48KB -> 3 blocks/CU (vs R2's 80KB -> 2). Gather
// code is byte-for-byte R2 (52us at 2 blocks/CU); 1.5x waves on the latency-bound
// phase. Restage costs 2 extra barriers + same total staged bytes.
// Bs rows 256B, swizzle byte^=(n&7)<<4; Ms rows 256B, swizzle byte^=(row&7)<<4.
#define GBM 64

__global__ __launch_bounds__(256, 3) void sage_fused(
    const __half* __restrict__ feat16, const int* __restrict__ rowptr,
    const int* __restrict__ eidx, const float* __restrict__ invdeg,
    const __half* __restrict__ Wt, const float* __restrict__ bias,
    __half* __restrict__ out16,
    const int* __restrict__ batch, float* __restrict__ pooled,
    int M, int do_pool) {
    __shared__ __align__(16) __half Bs[128 * 128];   // ONE K-half of weights (32KB)
    __shared__ __align__(16) __half Ms[64 * 128];    // mean tile / pool staging (16KB)

    const int tid = threadIdx.x;
    const int wave = tid >> 6;
    const int lane = tid & 63;
    const int l15 = lane & 15;
    const int quad = lane >> 4;
    const int row0 = blockIdx.x * GBM;

    // ---- stage phase-1 B half (Wl: k=0..127) into LDS (swizzled) ----
    for (int id = tid; id < 128 * 16; id += 256) {
        int n = id >> 4;
        int c16 = (id & 15) * 16;                       // byte col within 256B row
        int off = (n * 256 + c16) ^ ((n & 7) << 4);
        *(half8*)((char*)Bs + off) = *(const half8*)(Wt + (size_t)n * 256 + (id & 15) * 8);
    }

    // ---- aggregate: 16 groups x 4 nodes each into Ms (R2 gather, unchanged) ----
    const int g16 = tid >> 4;          // 0..15
    const int sub = tid & 15;
    const int gbase = lane & 48;
    const size_t coff = (size_t)sub * 8;   // halves

    int begq[4], endq[4], pre0q[4], pre1q[4];
#pragma unroll
    for (int q = 0; q < 4; ++q) {
        int node = row0 + g16 + 16 * q;
        int bq = 0, eq = 0;
        if (node < M) { bq = rowptr[node]; eq = rowptr[node + 1]; }
        begq[q] = bq; endq[q] = eq;
    }
#pragma unroll
    for (int q = 0; q < 4; ++q) {
        int bq = begq[q], eq = endq[q];
        pre0q[q] = (eq > bq) ? eidx[min(bq + sub,      eq - 1)] : 0;
        pre1q[q] = (eq > bq) ? eidx[min(bq + 16 + sub, eq - 1)] : 0;
    }

#pragma unroll
    for (int q = 0; q < 4; ++q) {
        const int nloc = g16 + 16 * q;
        const int node = row0 + nloc;
        const int beg = begq[q], end = endq[q];
        const int deg = end - beg;

        float4 a[4], bb[4];
#pragma unroll
        for (int g = 0; g < 4; ++g) { a[g] = (float4){0.f,0.f,0.f,0.f}; bb[g] = (float4){0.f,0.f,0.f,0.f}; }

        for (int j0 = 0; j0 < deg; j0 += 16) {
            int idx[16];
            if (j0 == 0) {
#pragma unroll
                for (int k = 0; k < 16; ++k) idx[k] = __shfl(pre0q[q], gbase + k);
            } else if (j0 == 16) {
#pragma unroll
                for (int k = 0; k < 16; ++k) idx[k] = __shfl(pre1q[q], gbase + k);
            } else {
#pragma unroll
                for (int k = 0; k < 16; ++k) idx[k] = eidx[min(beg + j0 + k, end - 1)];
            }
            half8 v[16];
#pragma unroll
            for (int k = 0; k < 16; ++k)
                v[k] = *(const half8*)(feat16 + (size_t)idx[k] * 128 + coff);
            const int rem = deg - j0;
#pragma unroll
            for (int k = 0; k < 16; ++k) {
                const float w = (k < rem) ? 1.0f : 0.0f;
                const int g = k & 3;
                a[g].x  += w * (float)v[k][0];
                a[g].y  += w * (float)v[k][1];
                a[g].z  += w * (float)v[k][2];
                a[g].w  += w * (float)v[k][3];
                bb[g].x += w * (float)v[k][4];
                bb[g].y += w * (float)v[k][5];
                bb[g].z += w * (float)v[k][6];
                bb[g].w += w * (float)v[k][7];
            }
        }

        const float sc = (node < M) ? invdeg[node] : 1.0f;
        half8 r;
        r[0] = (_Float16)(((a[0].x + a[1].x) + (a[2].x + a[3].x)) * sc);
        r[1] = (_Float16)(((a[0].y + a[1].y) + (a[2].y + a[3].y)) * sc);
        r[2] = (_Float16)(((a[0].z + a[1].z) + (a[2].z + a[3].z)) * sc);
        r[3] = (_Float16)(((a[0].w + a[1].w) + (a[2].w + a[3].w)) * sc);
        r[4] = (_Float16)(((bb[0].x + bb[1].x) + (bb[2].x + bb[3].x)) * sc);
        r[5] = (_Float16)(((bb[0].y + bb[1].y) + (bb[2].y + bb[3].y)) * sc);
        r[6] = (_Float16)(((bb[0].z + bb[1].z) + (bb[2].z + bb[3].z)) * sc);
        r[7] = (_Float16)(((bb[0].w + bb[1].w) + (bb[2].w + bb[3].w)) * sc);
        int moff = (nloc * 256 + (int)sub * 16) ^ ((nloc & 7) << 4);
        *(half8*)((char*)Ms + moff) = r;
    }

    __syncthreads();   // Bs phase-1 + Ms ready

    // ---- A fragments ----
    const int arow = wave * 16 + l15;
    const int gi_a = min(row0 + arow, M - 1);
    half8 af[8];
#pragma unroll
    for (int kb = 0; kb < 4; ++kb) {
        int off = (arow * 256 + kb * 64 + quad * 16) ^ ((arow & 7) << 4);
        af[kb] = *(const half8*)((const char*)Ms + off);
    }
#pragma unroll
    for (int kb = 4; kb < 8; ++kb) {
        af[kb] = *(const half8*)(feat16 + (size_t)gi_a * 128 + (kb - 4) * 32 + quad * 8);
    }

    f32x4 acc[8];
#pragma unroll
    for (int t = 0; t < 8; ++t) acc[t] = (f32x4){0.f, 0.f, 0.f, 0.f};

    // ---- GEMM phase 1: mean @ Wl^T (kb 0..3) ----
#pragma unroll
    for (int t = 0; t < 8; ++t) {
        const int n = t * 16 + l15;
#pragma unroll
        for (int kb = 0; kb < 4; ++kb) {
            const int boff = (n * 256 + kb * 64 + quad * 16) ^ ((n & 7) << 4);
            const half8 b = *(const half8*)((const char*)Bs + boff);
            acc[t] = __builtin_amdgcn_mfma_f32_16x16x32_f16(af[kb], b, acc[t], 0, 0, 0);
        }
    }

    __syncthreads();   // all phase-1 Bs reads done

    // ---- restage Bs with Wr half (k=128..255) ----
    for (int id = tid; id < 128 * 16; id += 256) {
        int n = id >> 4;
        int c16 = (id & 15) * 16;
        int off = (n * 256 + c16) ^ ((n & 7) << 4);
        *(half8*)((char*)Bs + off) = *(const half8*)(Wt + (size_t)n * 256 + 128 + (id & 15) * 8);
    }

    __syncthreads();   // Bs phase-2 ready

    // ---- GEMM phase 2: x @ Wr^T (kb 4..7) ----
#pragma unroll
    for (int t = 0; t < 8; ++t) {
        const int n = t * 16 + l15;
#pragma unroll
        for (int kb = 0; kb < 4; ++kb) {
            const int boff = (n * 256 + kb * 64 + quad * 16) ^ ((n & 7) << 4);
            const half8 b = *(const half8*)((const char*)Bs + boff);
            acc[t] = __builtin_amdgcn_mfma_f32_16x16x32_f16(af[4 + kb], b, acc[t], 0, 0, 0);
        }
    }

    if (!do_pool) {
        // ---- epilogue: bias + relu -> out16 ----
#pragma unroll
        for (int r = 0; r < 4; ++r) {
            int gi = row0 + wave * 16 + quad * 4 + r;
            if (gi < M) {
#pragma unroll
                for (int t = 0; t < 8; ++t) {
                    int col = t * 16 + l15;
                    float v = fmaxf(acc[t][r] + bias[col], 0.f);
                    out16[(size_t)gi * 128 + col] = __float2half(v);
                }
            }
        }
    } else {
        // ---- epilogue: bias + relu -> Ms (fp16, swizzled), then pool over graph segments ----
        __syncthreads();   // all Ms(A) reads complete
#pragma unroll
        for (int r = 0; r < 4; ++r) {
            int lrow = wave * 16 + quad * 4 + r;
            int gi = row0 + lrow;
#pragma unroll
            for (int t = 0; t < 8; ++t) {
                int col = t * 16 + l15;
                float v = fmaxf(acc[t][r] + bias[col], 0.f);
                if (gi >= M) v = 0.f;
                int off = (lrow * 256 + col * 2) ^ ((lrow & 7) << 4);
                *(__half*)((char*)Ms + off) = __float2half(v);
            }
        }
        __syncthreads();
        if (tid < 128) {
            const int col = tid;
            int cur = batch[min(row0, M - 1)];
            float s = 0.f;
            for (int r = 0; r < 64; ++r) {
                int gr = batch[min(row0 + r, M - 1)];
                if (gr != cur) {
                    atomicAdd(&pooled[cur * 128 + col], s);
                    s = 0.f; cur = gr;
                }
                int off = (r * 256 + col * 2) ^ ((r & 7) << 4);
                s += __half2float(*(const __half*)((const char*)Ms + off));
            }
            atomicAdd(&pooled[cur * 128 + col], s);
        }
    }
}

// ================= final linear =================
__global__ void final_kernel(const float* __restrict__ pooled,
                             const int* __restrict__ gstart,
                             const float* __restrict__ Wlin, const float* __restrict__ blin,
                             float* __restrict__ out) {
    int g = blockIdx.x;
    int j = threadIdx.x;               // 0..31
    float inv = 1.0f / fmaxf((float)(gstart[g + 1] - gstart[g]), 1.0f);
    float sum = blin[j];
    const float* w = Wlin + j * 128;
    const float* p = pooled + (size_t)g * 128;
    for (int c = 0; c < 128; ++c) {
        sum += p[c] * inv * w[c];
    }
    out[g * 32 + j] = sum;
}

extern "C" void kernel_launch(void* const* d_in, const int* in_sizes, int n_in,
                              void* d_out, int out_size, void* d_ws, size_t ws_size,
                              hipStream_t stream) {
    const float* x    = (const float*)d_in[0];
    const int*   src  = (const int*)d_in[1];
    const int*   dst  = ((const int*)d_in[1]) + N_EDGES;
    const int*   batch= (const int*)d_in[2];
    const float* W1l  = (const float*)d_in[3];
    const float* b1   = (const float*)d_in[4];
    const float* W1r  = (const float*)d_in[5];
    const float* W2l  = (const float*)d_in[6];
    const float* b2   = (const float*)d_in[7];
    const float* W2r  = (const float*)d_in[8];
    const float* Wlin = (const float*)d_in[9];
    const float* blin = (const float*)d_in[10];
    float* out = (float*)d_out;

    __half* xh     = (__half*)d_ws;                 // 6,400,000 h
    __half* h1_16  = xh + 6400000;                  // 6,400,000 h
    __half* Wt1    = h1_16 + 6400000;               // 32,768 h
    __half* Wt2    = Wt1 + 32768;                   // 32,768 h
    float* invdeg  = (float*)(Wt2 + 32768);         // 50,000 f
    int*   gstart  = (int*)(invdeg + N_NODES);      // 65 i
    // contiguous zero region: degi, cursor, bsum, pooled
    int*   degi    = gstart + 65;                   // 50,000 i
    int*   cursor  = degi + N_NODES;                // 50,000 i
    int*   bsum    = cursor + N_NODES;              // 196 i
    float* pooled  = (float*)(bsum + N_SCAN_BLOCKS);// 8,192 f (zeroed)
    int*   rowptr  = (int*)(pooled + N_GRAPHS*HID); // 50,001 i
    int*   eidx    = rowptr + N_NODES + 1;          // 600,000 i

    // 1) zero counters + pooled accumulators
    zero_kernel<<<(ZERO_INTS + 255) / 256, 256, 0, stream>>>(degi);

    // 2) degrees + graph boundaries + weight casts
    deg_gst_w<<<DEG_BLOCKS + GST_BLOCKS + 16, 256, 0, stream>>>(
        dst, degi, batch, gstart, W1l, W1r, W2l, W2r, Wt1, Wt2);

    // 3) fused lookback scan
    scan_fused<<<N_SCAN_BLOCKS, 256, 0, stream>>>(degi, bsum, rowptr, invdeg);

    // 4) CSR fill + x->fp16 cast
    fill_cast<<<DEG_BLOCKS + (N_NODES * 128 / 4 + 255) / 256, 256, 0, stream>>>(
        src, dst, rowptr, cursor, eidx, x, xh);

    const int grid = (N_NODES + GBM - 1) / GBM;   // 782

    // 5) layer 1: agg + gemm fused
    sage_fused<<<grid, 256, 0, stream>>>(
        xh, rowptr, eidx, invdeg, Wt1, b1, h1_16, batch, pooled, N_NODES, 0);

    // 6) layer 2: agg + gemm + pool fused
    sage_fused<<<grid, 256, 0, stream>>>(
        h1_16, rowptr, eidx, invdeg, Wt2, b2, (__half*)0, batch, pooled, N_NODES, 1);

    // 7) final linear
    final_kernel<<<N_GRAPHS, 32, 0, stream>>>(pooled, gstart, Wlin, blin, out);
}